// Round 1
// baseline (1108.063 us; speedup 1.0000x reference)
//
#include <hip/hip_runtime.h>

// Problem constants (from reference): N=50000, E=1.6M, dims 512 -> 128 -> 64
#define IN_DIM  512
#define HID_DIM 128
#define OUT_DIM 64

// ---------------------------------------------------------------------------
// CSR build: degree histogram -> single-block scan -> scatter
// ---------------------------------------------------------------------------

__global__ void k_zero(int* __restrict__ p, int n) {
    int i = blockIdx.x * blockDim.x + threadIdx.x;
    if (i < n) p[i] = 0;
}

__global__ void k_hist(const int* __restrict__ rows, int* __restrict__ deg, int E) {
    int i = blockIdx.x * blockDim.x + threadIdx.x;
    if (i < E) atomicAdd(&deg[rows[i]], 1);
}

// Exclusive scan of deg[0..n) into row_ptr (and row_fill copy), single block of 1024.
__global__ __launch_bounds__(1024) void k_scan(const int* __restrict__ deg,
                                               int* __restrict__ row_ptr,
                                               int* __restrict__ row_fill,
                                               int n, int E) {
    __shared__ int s[1024];
    const int tid = threadIdx.x;
    const int CH = (n + 1023) >> 10;  // elements per thread
    const int base = tid * CH;

    int sum = 0;
    for (int i = 0; i < CH; ++i) {
        int idx = base + i;
        if (idx < n) sum += deg[idx];
    }
    s[tid] = sum;
    __syncthreads();
    // Hillis-Steele inclusive scan over 1024 thread-sums
    for (int off = 1; off < 1024; off <<= 1) {
        int v = (tid >= off) ? s[tid - off] : 0;
        __syncthreads();
        s[tid] += v;
        __syncthreads();
    }
    int running = (tid == 0) ? 0 : s[tid - 1];
    for (int i = 0; i < CH; ++i) {
        int idx = base + i;
        if (idx < n) {
            row_ptr[idx]  = running;
            row_fill[idx] = running;
            running += deg[idx];
        }
    }
    if (tid == 0) row_ptr[n] = E;
}

__global__ void k_scatter(const int* __restrict__ rows, const int* __restrict__ cols,
                          const float* __restrict__ ew, int* __restrict__ row_fill,
                          int* __restrict__ ccol, float* __restrict__ cw, int E) {
    int i = blockIdx.x * blockDim.x + threadIdx.x;
    if (i < E) {
        int r = rows[i];
        int p = atomicAdd(&row_fill[r], 1);
        ccol[p] = cols[i];
        cw[p]   = ew[i];
    }
}

// ---------------------------------------------------------------------------
// GEMM1: sup[n x 128] = x[n x 512] @ W1[512 x 128]
// Block = 128 threads (thread = output column), 16 rows per block.
// x loads are wave-uniform -> scalar pipe (s_load); VALU does pure FMA.
// ---------------------------------------------------------------------------
__global__ __launch_bounds__(128) void k_gemm1(const float* __restrict__ x,
                                               const float* __restrict__ W1,
                                               float* __restrict__ sup) {
    const int R = 16;
    const int row0 = blockIdx.x * R;
    const int tid  = threadIdx.x;

    float acc[R];
#pragma unroll
    for (int r = 0; r < R; ++r) acc[r] = 0.f;

    const float* xb = x + (size_t)row0 * IN_DIM;
    for (int k = 0; k < IN_DIM; k += 4) {
        float w0 = W1[(k + 0) * HID_DIM + tid];
        float w1 = W1[(k + 1) * HID_DIM + tid];
        float w2 = W1[(k + 2) * HID_DIM + tid];
        float w3 = W1[(k + 3) * HID_DIM + tid];
#pragma unroll
        for (int r = 0; r < R; ++r) {
            float4 xv = *reinterpret_cast<const float4*>(xb + r * IN_DIM + k);
            acc[r] = fmaf(xv.x, w0, acc[r]);
            acc[r] = fmaf(xv.y, w1, acc[r]);
            acc[r] = fmaf(xv.z, w2, acc[r]);
            acc[r] = fmaf(xv.w, w3, acc[r]);
        }
    }
#pragma unroll
    for (int r = 0; r < R; ++r)
        sup[(size_t)(row0 + r) * HID_DIM + tid] = acc[r];
}

// ---------------------------------------------------------------------------
// GEMM2: sup2[n x 64] = h[n x 128] @ W2[128 x 64]
// Block = 64 threads, 16 rows per block.
// ---------------------------------------------------------------------------
__global__ __launch_bounds__(64) void k_gemm2(const float* __restrict__ h,
                                              const float* __restrict__ W2,
                                              float* __restrict__ sup2) {
    const int R = 16;
    const int row0 = blockIdx.x * R;
    const int tid  = threadIdx.x;

    float acc[R];
#pragma unroll
    for (int r = 0; r < R; ++r) acc[r] = 0.f;

    const float* hb = h + (size_t)row0 * HID_DIM;
    for (int k = 0; k < HID_DIM; k += 4) {
        float w0 = W2[(k + 0) * OUT_DIM + tid];
        float w1 = W2[(k + 1) * OUT_DIM + tid];
        float w2 = W2[(k + 2) * OUT_DIM + tid];
        float w3 = W2[(k + 3) * OUT_DIM + tid];
#pragma unroll
        for (int r = 0; r < R; ++r) {
            float4 hv = *reinterpret_cast<const float4*>(hb + r * HID_DIM + k);
            acc[r] = fmaf(hv.x, w0, acc[r]);
            acc[r] = fmaf(hv.y, w1, acc[r]);
            acc[r] = fmaf(hv.z, w2, acc[r]);
            acc[r] = fmaf(hv.w, w3, acc[r]);
        }
    }
#pragma unroll
    for (int r = 0; r < R; ++r)
        sup2[(size_t)(row0 + r) * OUT_DIM + tid] = acc[r];
}

// ---------------------------------------------------------------------------
// CSR SpMM: out[row] = sum_e w_e * sup[col_e]  (+bias, optional relu)
// One block per row, thread = dim. Gather-only, no atomics.
// ---------------------------------------------------------------------------
template <int D, bool RELU>
__global__ void k_spmm(const int* __restrict__ rp, const int* __restrict__ ccol,
                       const float* __restrict__ cw, const float* __restrict__ sup,
                       const float* __restrict__ bias, float* __restrict__ out) {
    const int row = blockIdx.x;
    const int tid = threadIdx.x;
    int s = rp[row], e = rp[row + 1];

    float acc = 0.f;
    int i = s;
    for (; i + 1 < e; i += 2) {  // 2-edge unroll for a little ILP
        int   c0 = ccol[i],   c1 = ccol[i + 1];
        float w0 = cw[i],     w1 = cw[i + 1];
        acc = fmaf(w0, sup[(size_t)c0 * D + tid], acc);
        acc = fmaf(w1, sup[(size_t)c1 * D + tid], acc);
    }
    if (i < e)
        acc = fmaf(cw[i], sup[(size_t)ccol[i] * D + tid], acc);

    float v = acc + bias[tid];
    if (RELU) v = fmaxf(v, 0.f);
    out[(size_t)row * D + tid] = v;
}

// ---------------------------------------------------------------------------

extern "C" void kernel_launch(void* const* d_in, const int* in_sizes, int n_in,
                              void* d_out, int out_size, void* d_ws, size_t ws_size,
                              hipStream_t stream) {
    const float* x  = (const float*)d_in[0];
    const int*   ei = (const int*)d_in[1];   // [2, E] int32: rows then cols
    const float* ew = (const float*)d_in[2];
    const float* W1 = (const float*)d_in[3];
    const float* b1 = (const float*)d_in[4];
    const float* W2 = (const float*)d_in[5];
    const float* b2 = (const float*)d_in[6];
    float* out = (float*)d_out;

    const int n = in_sizes[0] / IN_DIM;  // 50000
    const int E = in_sizes[2];           // 1600000
    const int* rows = ei;
    const int* cols = ei + E;

    // Workspace layout (256B aligned slices)
    char* ws = (char*)d_ws;
    size_t off = 0;
    auto alloc = [&](size_t bytes) -> void* {
        off = (off + 255) & ~(size_t)255;
        void* p = ws + off;
        off += bytes;
        return p;
    };
    float* sup1     = (float*)alloc((size_t)n * HID_DIM * sizeof(float)); // reused as sup2
    float* h        = (float*)alloc((size_t)n * HID_DIM * sizeof(float));
    int*   deg      = (int*)alloc((size_t)n * sizeof(int));
    int*   row_ptr  = (int*)alloc((size_t)(n + 1) * sizeof(int));
    int*   row_fill = (int*)alloc((size_t)n * sizeof(int));
    int*   ccol     = (int*)alloc((size_t)E * sizeof(int));
    float* cw       = (float*)alloc((size_t)E * sizeof(float));
    float* sup2     = sup1;  // sup1 is dead after SpMM1

    // --- CSR build ---
    k_zero<<<(n + 255) / 256, 256, 0, stream>>>(deg, n);
    k_hist<<<(E + 255) / 256, 256, 0, stream>>>(rows, deg, E);
    k_scan<<<1, 1024, 0, stream>>>(deg, row_ptr, row_fill, n, E);
    k_scatter<<<(E + 255) / 256, 256, 0, stream>>>(rows, cols, ew, row_fill, ccol, cw, E);

    // --- Layer 1 ---
    k_gemm1<<<n / 16, 128, 0, stream>>>(x, W1, sup1);
    k_spmm<HID_DIM, true><<<n, HID_DIM, 0, stream>>>(row_ptr, ccol, cw, sup1, b1, h);

    // --- Layer 2 ---
    k_gemm2<<<n / 16, 64, 0, stream>>>(h, W2, sup2);
    k_spmm<OUT_DIM, false><<<n, OUT_DIM, 0, stream>>>(row_ptr, ccol, cw, sup2, b2, out);
}

// Round 2
// 707.980 us; speedup vs baseline: 1.5651x; 1.5651x over previous
//
#include <hip/hip_runtime.h>

// Problem constants (from reference): N=50000, E=1.6M, dims 512 -> 128 -> 64
#define IN_DIM  512
#define HID_DIM 128
#define OUT_DIM 64

// ---------------------------------------------------------------------------
// CSR build: degree histogram -> single-block scan -> scatter
// ---------------------------------------------------------------------------

__global__ void k_zero(int* __restrict__ p, int n) {
    int i = blockIdx.x * blockDim.x + threadIdx.x;
    if (i < n) p[i] = 0;
}

__global__ void k_hist(const int* __restrict__ rows, int* __restrict__ deg, int E) {
    int i = blockIdx.x * blockDim.x + threadIdx.x;
    if (i < E) atomicAdd(&deg[rows[i]], 1);
}

// Exclusive scan of deg[0..n) into row_ptr (and row_fill copy), single block of 1024.
__global__ __launch_bounds__(1024) void k_scan(const int* __restrict__ deg,
                                               int* __restrict__ row_ptr,
                                               int* __restrict__ row_fill,
                                               int n, int E) {
    __shared__ int s[1024];
    const int tid = threadIdx.x;
    const int CH = (n + 1023) >> 10;  // elements per thread
    const int base = tid * CH;

    int sum = 0;
    for (int i = 0; i < CH; ++i) {
        int idx = base + i;
        if (idx < n) sum += deg[idx];
    }
    s[tid] = sum;
    __syncthreads();
    for (int off = 1; off < 1024; off <<= 1) {
        int v = (tid >= off) ? s[tid - off] : 0;
        __syncthreads();
        s[tid] += v;
        __syncthreads();
    }
    int running = (tid == 0) ? 0 : s[tid - 1];
    for (int i = 0; i < CH; ++i) {
        int idx = base + i;
        if (idx < n) {
            row_ptr[idx]  = running;
            row_fill[idx] = running;
            running += deg[idx];
        }
    }
    if (tid == 0) row_ptr[n] = E;
}

__global__ void k_scatter(const int* __restrict__ rows, const int* __restrict__ cols,
                          const float* __restrict__ ew, int* __restrict__ row_fill,
                          int* __restrict__ ccol, float* __restrict__ cw, int E) {
    int i = blockIdx.x * blockDim.x + threadIdx.x;
    if (i < E) {
        int r = rows[i];
        int p = atomicAdd(&row_fill[r], 1);
        ccol[p] = cols[i];
        cw[p]   = ew[i];
    }
}

// ---------------------------------------------------------------------------
// Tiled register-blocked GEMM: C[n x DC] = A[n x DK] @ W[DK x DC]
// Block: 256 threads, 128-row x DC-col output tile, BK=16 K-steps.
// A staged TRANSPOSED in LDS (As[k][row]) -> thread's TM row-values are
// contiguous (ds_read_b128). W staged row-major (Ws[k][col], b128 reads).
// Thread microtile: TM=8 rows x TN cols (TN=8 for DC=128, TN=4 for DC=64).
// Per k: TM*TN FMAs (128/64 cyc per wave) vs ~4 b128 LDS reads -> VALU-bound.
// ---------------------------------------------------------------------------
template <int DK, int DC, int TN>
__global__ __launch_bounds__(256) void k_gemm(const float* __restrict__ A,
                                              const float* __restrict__ W,
                                              float* __restrict__ C, int n) {
    constexpr int BR = 128, BK = 16, TM = 8;
    constexpr int TX = DC / TN;          // 16 in both instantiations
    static_assert(TX * (BR / TM) == 256, "thread layout");

    __shared__ float As[BK][BR];         // A tile, transposed
    __shared__ float Ws[BK][DC];         // W tile, row-major

    const int tid  = threadIdx.x;
    const int tx   = tid % TX;           // col group
    const int ty   = tid / TX;           // row group [0,16)
    const int row0 = blockIdx.x * BR;

    float acc[TM][TN];
#pragma unroll
    for (int i = 0; i < TM; ++i)
#pragma unroll
        for (int j = 0; j < TN; ++j) acc[i][j] = 0.f;

    for (int k0 = 0; k0 < DK; k0 += BK) {
        __syncthreads();  // previous compute done before LDS overwrite

        // --- stage A: BR*BK = 2048 floats = 512 float4, 2 per thread ---
#pragma unroll
        for (int l = 0; l < 2; ++l) {
            int q   = tid + l * 256;
            int row = q & 127;
            int kq  = q >> 7;            // 0..3 (float4 quad within BK)
            int rr  = row0 + row;
            if (rr >= n) rr = n - 1;     // clamp (dup row, discarded at store)
            float4 v = *reinterpret_cast<const float4*>(&A[(size_t)rr * DK + k0 + 4 * kq]);
            As[4 * kq + 0][row] = v.x;
            As[4 * kq + 1][row] = v.y;
            As[4 * kq + 2][row] = v.z;
            As[4 * kq + 3][row] = v.w;
        }
        // --- stage W: BK*DC floats, coalesced float4 ---
        constexpr int WL = (BK * DC / 4) / 256;  // 2 for DC=128, 1 for DC=64
#pragma unroll
        for (int l = 0; l < WL; ++l) {
            int q = tid + l * 256;
            int k = (q * 4) / DC;
            int c = (q * 4) % DC;
            *reinterpret_cast<float4*>(&Ws[k][c]) =
                *reinterpret_cast<const float4*>(&W[(size_t)(k0 + k) * DC + c]);
        }
        __syncthreads();

        // --- compute ---
#pragma unroll
        for (int k = 0; k < BK; ++k) {
            float a[TM], w[TN];
#pragma unroll
            for (int i = 0; i < TM; i += 4) {
                float4 v = *reinterpret_cast<const float4*>(&As[k][ty * TM + i]);
                a[i] = v.x; a[i + 1] = v.y; a[i + 2] = v.z; a[i + 3] = v.w;
            }
#pragma unroll
            for (int j = 0; j < TN; j += 4) {
                float4 v = *reinterpret_cast<const float4*>(&Ws[k][tx * TN + j]);
                w[j] = v.x; w[j + 1] = v.y; w[j + 2] = v.z; w[j + 3] = v.w;
            }
#pragma unroll
            for (int i = 0; i < TM; ++i)
#pragma unroll
                for (int j = 0; j < TN; ++j)
                    acc[i][j] = fmaf(a[i], w[j], acc[i][j]);
        }
    }

    // --- store (guarded rows, vectorized) ---
#pragma unroll
    for (int i = 0; i < TM; ++i) {
        int r = row0 + ty * TM + i;
        if (r < n) {
#pragma unroll
            for (int j = 0; j < TN; j += 4) {
                float4 v = make_float4(acc[i][j], acc[i][j + 1], acc[i][j + 2], acc[i][j + 3]);
                *reinterpret_cast<float4*>(&C[(size_t)r * DC + tx * TN + j]) = v;
            }
        }
    }
}

// ---------------------------------------------------------------------------
// CSR SpMM: out[row] = sum_e w_e * sup[col_e]  (+bias, optional relu)
// One block per row, thread = dim. Gather-only, no atomics.
// 4-wide unroll: 4 independent gathers in flight per iteration.
// ---------------------------------------------------------------------------
template <int D, bool RELU>
__global__ void k_spmm(const int* __restrict__ rp, const int* __restrict__ ccol,
                       const float* __restrict__ cw, const float* __restrict__ sup,
                       const float* __restrict__ bias, float* __restrict__ out) {
    const int row = blockIdx.x;
    const int tid = threadIdx.x;
    int s = rp[row], e = rp[row + 1];

    float acc = 0.f;
    int i = s;
    for (; i + 4 <= e; i += 4) {
        int   c0 = ccol[i],     c1 = ccol[i + 1], c2 = ccol[i + 2], c3 = ccol[i + 3];
        float w0 = cw[i],       w1 = cw[i + 1],   w2 = cw[i + 2],   w3 = cw[i + 3];
        float v0 = sup[(size_t)c0 * D + tid];
        float v1 = sup[(size_t)c1 * D + tid];
        float v2 = sup[(size_t)c2 * D + tid];
        float v3 = sup[(size_t)c3 * D + tid];
        acc = fmaf(w0, v0, acc);
        acc = fmaf(w1, v1, acc);
        acc = fmaf(w2, v2, acc);
        acc = fmaf(w3, v3, acc);
    }
    for (; i < e; ++i)
        acc = fmaf(cw[i], sup[(size_t)ccol[i] * D + tid], acc);

    float v = acc + bias[tid];
    if (RELU) v = fmaxf(v, 0.f);
    out[(size_t)row * D + tid] = v;
}

// ---------------------------------------------------------------------------

extern "C" void kernel_launch(void* const* d_in, const int* in_sizes, int n_in,
                              void* d_out, int out_size, void* d_ws, size_t ws_size,
                              hipStream_t stream) {
    const float* x  = (const float*)d_in[0];
    const int*   ei = (const int*)d_in[1];   // [2, E] rows then cols
    const float* ew = (const float*)d_in[2];
    const float* W1 = (const float*)d_in[3];
    const float* b1 = (const float*)d_in[4];
    const float* W2 = (const float*)d_in[5];
    const float* b2 = (const float*)d_in[6];
    float* out = (float*)d_out;

    const int n = in_sizes[0] / IN_DIM;  // 50000
    const int E = in_sizes[2];           // 1600000
    const int* rows = ei;
    const int* cols = ei + E;

    // Workspace layout (256B aligned slices)
    char* ws = (char*)d_ws;
    size_t off = 0;
    auto alloc = [&](size_t bytes) -> void* {
        off = (off + 255) & ~(size_t)255;
        void* p = ws + off;
        off += bytes;
        return p;
    };
    float* sup1     = (float*)alloc((size_t)n * HID_DIM * sizeof(float)); // reused as sup2
    float* h        = (float*)alloc((size_t)n * HID_DIM * sizeof(float));
    int*   deg      = (int*)alloc((size_t)n * sizeof(int));
    int*   row_ptr  = (int*)alloc((size_t)(n + 1) * sizeof(int));
    int*   row_fill = (int*)alloc((size_t)n * sizeof(int));
    int*   ccol     = (int*)alloc((size_t)E * sizeof(int));
    float* cw       = (float*)alloc((size_t)E * sizeof(float));
    float* sup2     = sup1;  // sup1 dead after SpMM1

    const int gemm_blocks = (n + 127) / 128;  // 391

    // --- CSR build ---
    k_zero<<<(n + 255) / 256, 256, 0, stream>>>(deg, n);
    k_hist<<<(E + 255) / 256, 256, 0, stream>>>(rows, deg, E);
    k_scan<<<1, 1024, 0, stream>>>(deg, row_ptr, row_fill, n, E);
    k_scatter<<<(E + 255) / 256, 256, 0, stream>>>(rows, cols, ew, row_fill, ccol, cw, E);

    // --- Layer 1 ---
    k_gemm<IN_DIM, HID_DIM, 8><<<gemm_blocks, 256, 0, stream>>>(x, W1, sup1, n);
    k_spmm<HID_DIM, true><<<n, HID_DIM, 0, stream>>>(row_ptr, ccol, cw, sup1, b1, h);

    // --- Layer 2 ---
    k_gemm<HID_DIM, OUT_DIM, 4><<<gemm_blocks, 256, 0, stream>>>(h, W2, sup2, n);
    k_spmm<OUT_DIM, false><<<n, OUT_DIM, 0, stream>>>(row_ptr, ccol, cw, sup2, b2, out);
}